// Round 1
// baseline (429.175 us; speedup 1.0000x reference)
//
#include <hip/hip_runtime.h>
#include <cstddef>

// Problem constants (fixed by the reference):
//   G=1024 graphs x 64 nodes, V=32, H=128, DIN=128, DOUT=10, E=1048576.
// Strategy: edges never cross 64-node graph blocks -> build dense per-graph
// 64x64 adjacency A (atomicAdd, counts multiplicity), then ONE fused kernel,
// one block per graph, everything staged in LDS (gfx950: 160KB/WG).
#define EDGES 1048576
#define PAD   132   // padded row stride for 64x128 activation tiles (bank spread)

__global__ __launch_bounds__(256) void build_adj(const int* __restrict__ ei,
                                                 float* __restrict__ A)
{
    int e = blockIdx.x * 256 + threadIdx.x;
    int s = ei[e];
    int d = ei[EDGES + e];
    int g = s >> 6;
    // A[g][dst_local][src_local] += 1  (float adds of 1.0 are exact/deterministic)
    atomicAdd(A + (((size_t)g) << 12) + ((size_t)(d & 63) << 6) + (s & 63), 1.0f);
}

__device__ __forceinline__ float sigmoidf_(float x) {
    return 1.0f / (1.0f + __expf(-x));
}

// out[M x 128] = in[M x 128] @ W[128 x 128] (+bias)(+relu); W staged from
// global into sWbuf in two 64-row halves. Thread tile: TM rows x 8 cols.
template<int M, bool RELU, bool BIAS>
__device__ __forceinline__ void gemm_g(const float* __restrict__ gW,
                                       const float* __restrict__ gB,
                                       const float* sIn, float* sOut,
                                       float* sWbuf, int tid)
{
    static_assert(M == 64 || M == 32, "");
    constexpr int TM = M / 16;
    const int rg = tid >> 4;          // 0..15
    const int cg = tid & 15;          // 0..15
    const int n0 = rg * TM;
    const int j0 = cg * 8;
    float acc[TM][8];
#pragma unroll
    for (int i = 0; i < TM; ++i)
#pragma unroll
        for (int j = 0; j < 8; ++j) acc[i][j] = 0.f;

    for (int kh = 0; kh < 2; ++kh) {
        __syncthreads();   // prior consumers of sWbuf / producers of sIn done
        {
            const float4* src = (const float4*)(gW + kh * 64 * 128);
            float4* dst = (float4*)sWbuf;
#pragma unroll
            for (int t = 0; t < 8; ++t) dst[tid + t * 256] = src[tid + t * 256];
        }
        __syncthreads();
        const float* inb = sIn + kh * 64;
        for (int k = 0; k < 64; k += 4) {
            float a[TM][4];
#pragma unroll
            for (int i = 0; i < TM; ++i)
                *(float4*)&a[i][0] = *(const float4*)(inb + (n0 + i) * PAD + k);
#pragma unroll
            for (int kk = 0; kk < 4; ++kk) {
                float b[8];
                *(float4*)&b[0] = *(const float4*)(sWbuf + (k + kk) * 128 + j0);
                *(float4*)&b[4] = *(const float4*)(sWbuf + (k + kk) * 128 + j0 + 4);
#pragma unroll
                for (int i = 0; i < TM; ++i) {
                    float av = a[i][kk];
#pragma unroll
                    for (int j = 0; j < 8; ++j)
                        acc[i][j] = fmaf(av, b[j], acc[i][j]);
                }
            }
        }
    }
#pragma unroll
    for (int i = 0; i < TM; ++i)
#pragma unroll
        for (int j = 0; j < 8; ++j) {
            float v = acc[i][j];
            if (BIAS) v += gB[j0 + j];
            if (RELU) v = fmaxf(v, 0.f);
            sOut[(n0 + i) * PAD + j0 + j] = v;
        }
}

// h_gcn[d][c] = relu( inv[d] * sum_s A'[d][s]*hws[s][c] + b_gcn[c] )
// A' includes self-loop identity; hws already scaled by inv[s].
__device__ __forceinline__ void agg_gemm(const float* sA, const float* sHW,
                                         float* sOut, const float* sInv,
                                         const float* __restrict__ b_gcn, int tid)
{
    const int rg = tid >> 4, cg = tid & 15;
    const int n0 = rg * 4, j0 = cg * 8;
    float acc[4][8];
#pragma unroll
    for (int i = 0; i < 4; ++i)
#pragma unroll
        for (int j = 0; j < 8; ++j) acc[i][j] = 0.f;
    for (int k = 0; k < 64; k += 4) {
        float a[4][4];
#pragma unroll
        for (int i = 0; i < 4; ++i)
            *(float4*)&a[i][0] = *(const float4*)(sA + (n0 + i) * 64 + k);
#pragma unroll
        for (int kk = 0; kk < 4; ++kk) {
            float b[8];
            *(float4*)&b[0] = *(const float4*)(sHW + (k + kk) * PAD + j0);
            *(float4*)&b[4] = *(const float4*)(sHW + (k + kk) * PAD + j0 + 4);
#pragma unroll
            for (int i = 0; i < 4; ++i) {
                float av = a[i][kk];
#pragma unroll
                for (int j = 0; j < 8; ++j)
                    acc[i][j] = fmaf(av, b[j], acc[i][j]);
            }
        }
    }
#pragma unroll
    for (int i = 0; i < 4; ++i) {
        float s = sInv[n0 + i];
#pragma unroll
        for (int j = 0; j < 8; ++j) {
            float v = fmaf(acc[i][j], s, b_gcn[j0 + j]);
            sOut[(n0 + i) * PAD + j0 + j] = fmaxf(v, 0.f);
        }
    }
}

// M2g[k][v] = sum_j aff_W2[k][j] * vembT[j][v]   (128x32 out, into sM)
__device__ __forceinline__ void m2g_gemm(const float* __restrict__ gW2,
                                         const float* sVT, float* sM,
                                         float* sWbuf, int tid)
{
    const int rg = tid >> 3;   // 0..31 -> 2 k-rows within the staged half
    const int cg = tid & 7;    // v0 = cg*4
    const int v0 = cg * 4;
    for (int kh = 0; kh < 2; ++kh) {
        float acc[2][4];
#pragma unroll
        for (int i = 0; i < 2; ++i)
#pragma unroll
            for (int j = 0; j < 4; ++j) acc[i][j] = 0.f;
        __syncthreads();
        {
            const float4* src = (const float4*)(gW2 + kh * 64 * 128);
            float4* dst = (float4*)sWbuf;
#pragma unroll
            for (int t = 0; t < 8; ++t) dst[tid + t * 256] = src[tid + t * 256];
        }
        __syncthreads();
        const int r0 = rg * 2;
        for (int j = 0; j < 128; j += 4) {
            float a0[4], a1[4];
            *(float4*)&a0[0] = *(const float4*)(sWbuf + r0 * 128 + j);
            *(float4*)&a1[0] = *(const float4*)(sWbuf + (r0 + 1) * 128 + j);
#pragma unroll
            for (int jj = 0; jj < 4; ++jj) {
                float b[4];
                *(float4*)&b[0] = *(const float4*)(sVT + (j + jj) * 36 + v0);
#pragma unroll
                for (int t = 0; t < 4; ++t) {
                    acc[0][t] = fmaf(a0[jj], b[t], acc[0][t]);
                    acc[1][t] = fmaf(a1[jj], b[t], acc[1][t]);
                }
            }
        }
        const int kg = kh * 64 + r0;
        *(float4*)(sM + kg * 32 + v0)       = make_float4(acc[0][0], acc[0][1], acc[0][2], acc[0][3]);
        *(float4*)(sM + (kg + 1) * 32 + v0) = make_float4(acc[1][0], acc[1][1], acc[1][2], acc[1][3]);
    }
}

// att -> ew (sigmoid gate, row-normalize over V=32) -> sEw[64][32]
__device__ __forceinline__ void att_gemm(const float* sAffh, const float* sM,
                                         const float* sBatt,
                                         const float* __restrict__ gEw,
                                         float* sEw, int tid, int g)
{
    const int rg = tid >> 4, cg = tid & 15;
    const int n0 = rg * 4, v0 = cg * 2;
    float acc[4][2];
#pragma unroll
    for (int i = 0; i < 4; ++i) { acc[i][0] = 0.f; acc[i][1] = 0.f; }
    for (int k = 0; k < 128; k += 4) {
        float a[4][4];
#pragma unroll
        for (int i = 0; i < 4; ++i)
            *(float4*)&a[i][0] = *(const float4*)(sAffh + (n0 + i) * PAD + k);
#pragma unroll
        for (int kk = 0; kk < 4; ++kk) {
            float2 b = *(const float2*)(sM + (k + kk) * 32 + v0);
#pragma unroll
            for (int i = 0; i < 4; ++i) {
                acc[i][0] = fmaf(a[i][kk], b.x, acc[i][0]);
                acc[i][1] = fmaf(a[i][kk], b.y, acc[i][1]);
            }
        }
    }
    const float scale = 0.08838834764831845f;  // 1/sqrt(128)
    float ew[4][2];
#pragma unroll
    for (int i = 0; i < 4; ++i)
#pragma unroll
        for (int j = 0; j < 2; ++j) {
            float att = (acc[i][j] + sBatt[v0 + j]) * scale;
            float w = gEw[(size_t)g * 2048 + (n0 + i) * 32 + v0 + j];
            ew[i][j] = w * (1.f + sigmoidf_(att));
        }
#pragma unroll
    for (int i = 0; i < 4; ++i) {
        float rs = ew[i][0] + ew[i][1];
        rs += __shfl_xor(rs, 1);
        rs += __shfl_xor(rs, 2);
        rs += __shfl_xor(rs, 4);
        rs += __shfl_xor(rs, 8);   // full 16-lane (same-row) sum
        float r = 1.f / rs;
        *(float2*)(sEw + (n0 + i) * 32 + v0) = make_float2(ew[i][0] * r, ew[i][1] * r);
    }
}

// vn[v][c] = sum_n ew[n][v] * hgcn[n][c]   (32x128 out into sOut rows 0..31)
__device__ __forceinline__ void pool_gemm(const float* sEw, const float* sH,
                                          float* sOut, int tid)
{
    const int rg = tid >> 4, cg = tid & 15;
    const int v0 = rg * 2, c0 = cg * 8;
    float acc[2][8];
#pragma unroll
    for (int i = 0; i < 2; ++i)
#pragma unroll
        for (int j = 0; j < 8; ++j) acc[i][j] = 0.f;
    for (int n = 0; n < 64; ++n) {
        float2 a = *(const float2*)(sEw + n * 32 + v0);
        float b[8];
        *(float4*)&b[0] = *(const float4*)(sH + n * PAD + c0);
        *(float4*)&b[4] = *(const float4*)(sH + n * PAD + c0 + 4);
#pragma unroll
        for (int j = 0; j < 8; ++j) {
            acc[0][j] = fmaf(a.x, b[j], acc[0][j]);
            acc[1][j] = fmaf(a.y, b[j], acc[1][j]);
        }
    }
#pragma unroll
    for (int i = 0; i < 2; ++i)
#pragma unroll
        for (int j = 0; j < 8; ++j)
            sOut[(v0 + i) * PAD + c0 + j] = acc[i][j];
}

__global__ __launch_bounds__(256) void fused_graph(
    const float* __restrict__ x, const float* __restrict__ edge_w,
    const float* __restrict__ vemb,
    const float* __restrict__ W_emb,  const float* __restrict__ b_emb,
    const float* __restrict__ W_gcn,  const float* __restrict__ b_gcn,
    const float* __restrict__ aff_W1, const float* __restrict__ aff_b1,
    const float* __restrict__ aff_W2, const float* __restrict__ aff_b2,
    const float* __restrict__ vn_W1,  const float* __restrict__ vn_b1,
    const float* __restrict__ vn_W2,  const float* __restrict__ vn_b2,
    const float* __restrict__ mlp_W1, const float* __restrict__ mlp_b1,
    const float* __restrict__ mlp_W2, const float* __restrict__ mlp_b2,
    const float* __restrict__ Abuf, float* __restrict__ out)
{
    __shared__ float sB0[64 * PAD];    // 33.0 KB  activations (ping)
    __shared__ float sB1[64 * PAD];    // 33.0 KB  activations (pong)
    __shared__ float sW [64 * 128];    // 32.0 KB  weight half
    __shared__ float sA [64 * 64];     // 16.0 KB  adjacency, later M2g[128][32]
    __shared__ float sVT[128 * 36];    // 18.0 KB  vemb^T, padded stride 36
    __shared__ float sAtt[64 * 32];    //  8.0 KB  normalized ew
    __shared__ float sInv[64];
    __shared__ float sGf[128];
    __shared__ float sZ[128];
    __shared__ float sBatt[32];
    // total ~144.8 KB < 160 KB (gfx950) -> 1 block/CU

    const int tid = threadIdx.x;
    const int g = blockIdx.x;

    // ---- stage x tile -> sB0 ----
    {
        const float4* gx = (const float4*)(x + (size_t)g * 64 * 128);
#pragma unroll
        for (int t = 0; t < 8; ++t) {
            int i = tid + t * 256;
            int row = i >> 5, c4 = i & 31;
            *(float4*)(sB0 + row * PAD + c4 * 4) = gx[i];
        }
    }
    // ---- stage adjacency, compute inv = rsqrt(indeg+1) ----
    {
        const float4* gA = (const float4*)(Abuf + ((size_t)g << 12));
        int row = tid >> 2, q = tid & 3;
        float rs = 0.f;
#pragma unroll
        for (int t = 0; t < 4; ++t) {
            float4 v = gA[tid * 4 + t];
            *(float4*)(sA + row * 64 + q * 16 + t * 4) = v;
            rs += v.x + v.y + v.z + v.w;
        }
        rs += __shfl_xor(rs, 1);
        rs += __shfl_xor(rs, 2);
        if (q == 0) sInv[row] = rsqrtf(rs + 1.0f);
    }
    // ---- stage vemb transposed: sVT[j][v], stride 36 ----
    {
        const float* gv = vemb + (size_t)g * 4096;
#pragma unroll
        for (int t = 0; t < 16; ++t) {
            int i = tid + t * 256;
            int v = i >> 7, j = i & 127;
            sVT[j * 36 + v] = gv[i];
        }
    }
    __syncthreads();
    if (tid < 64) sA[tid * 64 + tid] += 1.0f;   // self-loop

    // h = x @ W_emb + b_emb
    gemm_g<64, false, true >(W_emb, b_emb, sB0, sB1, sW, tid);
    // hw = h @ W_gcn
    gemm_g<64, false, false>(W_gcn, nullptr, sB1, sB0, sW, tid);
    __syncthreads();
    // hws = inv[s] * hw (row scale in place)
#pragma unroll
    for (int t = 0; t < 8; ++t) {
        int i = tid + t * 256;
        int row = i >> 5, c4 = i & 31;
        float s = sInv[row];
        float4* p = (float4*)(sB0 + row * PAD + c4 * 4);
        float4 v = *p;
        v.x *= s; v.y *= s; v.z *= s; v.w *= s;
        *p = v;
    }
    __syncthreads();
    // h_gcn = relu(inv[d] * (A' @ hws) + b_gcn)   -> sB1
    agg_gemm(sA, sB0, sB1, sInv, b_gcn, tid);
    // affh = relu(h_gcn @ aff_W1 + aff_b1)        -> sB0   (internal sync covers agg)
    gemm_g<64, true, true>(aff_W1, aff_b1, sB1, sB0, sW, tid);
    // M2g = aff_W2 @ vemb^T -> sA ;  batt = aff_b2 @ vemb^T
    m2g_gemm(aff_W2, sVT, sA, sW, tid);
    if (tid < 32) {
        float s = 0.f;
        for (int j = 0; j < 128; ++j) s += aff_b2[j] * sVT[j * 36 + tid];
        sBatt[tid] = s;
    }
    __syncthreads();
    // att = (affh @ M2g + batt)/sqrt(H); ew = norm(edge_w*(1+sigmoid(att))) -> sAtt
    att_gemm(sB0, sA, sBatt, edge_w, sAtt, tid, g);
    __syncthreads();
    // vn = ew^T @ h_gcn -> sB0 rows 0..31
    pool_gemm(sAtt, sB1, sB0, tid);
    // vn1 = relu(vn @ vn_W1 + b) -> sB0 rows 32..63 ; vn2 = vn1 @ vn_W2 + b -> sB1
    gemm_g<32, true,  true>(vn_W1, vn_b1, sB0, sB0 + 32 * PAD, sW, tid);
    gemm_g<32, false, true>(vn_W2, vn_b2, sB0 + 32 * PAD, sB1, sW, tid);
    __syncthreads();
    // gf = mean over V
    if (tid < 128) {
        float s = 0.f;
#pragma unroll
        for (int v = 0; v < 32; ++v) s += sB1[v * PAD + tid];
        sGf[tid] = s * (1.f / 32.f);
    }
    __syncthreads();
    // z = relu(gf @ mlp_W1 + b1)
    if (tid < 128) {
        float a = mlp_b1[tid];
        for (int k = 0; k < 128; ++k) a = fmaf(sGf[k], mlp_W1[k * 128 + tid], a);
        sZ[tid] = fmaxf(a, 0.f);
    }
    __syncthreads();
    // out = z @ mlp_W2 + b2   (10 outputs; 16 lanes/output, shuffle-reduce)
    if (tid < 160) {
        int o = tid >> 4, jg = tid & 15;
        float p = 0.f;
#pragma unroll
        for (int t = 0; t < 8; ++t) {
            int j = jg * 8 + t;
            p = fmaf(sZ[j], mlp_W2[j * 10 + o], p);
        }
        p += __shfl_xor(p, 1);
        p += __shfl_xor(p, 2);
        p += __shfl_xor(p, 4);
        p += __shfl_xor(p, 8);
        if (jg == 0) out[g * 10 + o] = p + mlp_b2[o];
    }
}

extern "C" void kernel_launch(void* const* d_in, const int* in_sizes, int n_in,
                              void* d_out, int out_size, void* d_ws, size_t ws_size,
                              hipStream_t stream)
{
    const float* x       = (const float*)d_in[0];
    const int*   ei      = (const int*)  d_in[1];
    // d_in[2] = batch (unused; nodes are contiguous 64-blocks per graph)
    const float* edge_w  = (const float*)d_in[3];
    const float* vemb    = (const float*)d_in[4];
    const float* W_emb   = (const float*)d_in[5];
    const float* b_emb   = (const float*)d_in[6];
    const float* W_gcn   = (const float*)d_in[7];
    const float* b_gcn   = (const float*)d_in[8];
    const float* aff_W1  = (const float*)d_in[9];
    const float* aff_b1  = (const float*)d_in[10];
    const float* aff_W2  = (const float*)d_in[11];
    const float* aff_b2  = (const float*)d_in[12];
    const float* vn_W1   = (const float*)d_in[13];
    const float* vn_b1   = (const float*)d_in[14];
    const float* vn_W2   = (const float*)d_in[15];
    const float* vn_b2   = (const float*)d_in[16];
    const float* mlp_W1  = (const float*)d_in[17];
    const float* mlp_b1  = (const float*)d_in[18];
    const float* mlp_W2  = (const float*)d_in[19];
    const float* mlp_b2  = (const float*)d_in[20];

    float* A = (float*)d_ws;                       // 1024*64*64 floats = 16 MB
    hipMemsetAsync(A, 0, (size_t)1024 * 64 * 64 * sizeof(float), stream);
    build_adj<<<dim3(EDGES / 256), dim3(256), 0, stream>>>(ei, A);
    fused_graph<<<dim3(1024), dim3(256), 0, stream>>>(
        x, edge_w, vemb, W_emb, b_emb, W_gcn, b_gcn,
        aff_W1, aff_b1, aff_W2, aff_b2, vn_W1, vn_b1, vn_W2, vn_b2,
        mlp_W1, mlp_b1, mlp_W2, mlp_b2, A, (float*)d_out);
}

// Round 2
// 257.396 us; speedup vs baseline: 1.6674x; 1.6674x over previous
//
#include <hip/hip_runtime.h>
#include <hip/hip_bf16.h>
#include <cstddef>

// G=1024 x 64 nodes, V=32, H=128, DIN=128, DOUT=10, E=1048576.
// R2: all eight inner GEMMs on bf16 MFMA (16x16x32, fp32 acc).
//  - weights pre-converted to bf16 (transposed [out][in] for feat-contraction
//    GEMMs) once per launch; B-fragments read straight from global/L2.
//  - activations bf16 in LDS; MFMA D-layout (col=lane&15,row=quad*4+reg)
//    packs naturally into TRANSPOSED [feat][node] buffers == exactly the
//    B-operand layout the node-contraction GEMMs (agg, pool) need.
//  - adjacency packed 2 x u16 counts per u32 word (8 MB ws).
//  - LDS 81,280 B -> 2 blocks/CU (8 waves) vs R1's 1 block (4 waves).

#define EDGES 1048576
#define SR 136   // row stride (bf16 elems) of row-major [node][feat] buffers
#define ST 72    // row stride of transposed [feat][node] buffers

typedef __attribute__((ext_vector_type(8))) short short8;
typedef __attribute__((ext_vector_type(4))) float f32x4;
typedef __hip_bfloat16 bf;

struct __align__(8) bf4 { bf v[4]; };

__global__ __launch_bounds__(256) void build_adj(const int* __restrict__ ei,
                                                 unsigned* __restrict__ A)
{
    int e = blockIdx.x * 256 + threadIdx.x;
    int s = ei[e];
    int d = ei[EDGES + e];
    int g = s >> 6;
    // word = g*2048 + dloc*32 + sloc/2 ; lo half = even sloc, hi half = odd
    unsigned idx = ((unsigned)g << 11) + ((unsigned)(d & 63) << 5) + ((unsigned)(s & 63) >> 1);
    atomicAdd(A + idx, 1u << ((s & 1) * 16));
}

// ws+8MB layout: [0]=W_emb^T [1]=W_gcn^T [2]=aff_W1^T [3]=aff_W2 (straight)
//                [4]=vn_W1^T [5]=vn_W2^T   (each 128x128 bf16, row-major)
__global__ __launch_bounds__(256) void conv_weights(
    const float* __restrict__ w0, const float* __restrict__ w1,
    const float* __restrict__ w2, const float* __restrict__ w3,
    const float* __restrict__ w4, const float* __restrict__ w5,
    bf* __restrict__ out)
{
    int m = blockIdx.y;
    const float* src = m==0?w0: m==1?w1: m==2?w2: m==3?w3: m==4?w4: w5;
    int idx = blockIdx.x * 256 + threadIdx.x;   // 64 blocks x -> 16384
    float v;
    if (m == 3) v = src[idx];
    else { int o = idx >> 7, i = idx & 127; v = src[i * 128 + o]; }
    out[m * 16384 + idx] = __float2bfloat16(v);
}

// KSTEPS k-chunks of 32; A row rowA (incl lane&15), B rows rowB + nt*16
// (rowB incl lane&15). Works for LDS or global B (SB = row stride, elems).
template<int SA, int SB, int KSTEPS, int NT>
__device__ __forceinline__ void mma_block(const bf* sA, const bf* sB,
                                          int rowA, int rowB, int kofs, f32x4* acc)
{
#pragma unroll
    for (int ks = 0; ks < KSTEPS; ++ks) {
        short8 a = *(const short8*)(sA + rowA * SA + ks * 32 + kofs);
#pragma unroll
        for (int nt = 0; nt < NT; ++nt) {
            short8 b = *(const short8*)(sB + (rowB + nt * 16) * SB + ks * 32 + kofs);
            acc[nt] = __builtin_amdgcn_mfma_f32_16x16x32_bf16(a, b, acc[nt], 0, 0, 0);
        }
    }
}

__global__ __launch_bounds__(256, 2) void fused_graph(
    const float* __restrict__ x, const float* __restrict__ edge_w,
    const float* __restrict__ vemb,
    const bf* __restrict__ gWb,            // 6 bf16 matrices (see conv_weights)
    const float* __restrict__ b_emb,  const float* __restrict__ b_gcn,
    const float* __restrict__ aff_b1, const float* __restrict__ aff_b2,
    const float* __restrict__ vn_b1,  const float* __restrict__ vn_b2,
    const float* __restrict__ mlp_W1, const float* __restrict__ mlp_b1,
    const float* __restrict__ mlp_W2, const float* __restrict__ mlp_b2,
    const unsigned* __restrict__ Awords, float* __restrict__ out)
{
    __shared__ __align__(16) bf sRM1[64 * SR];   // 17,408 B row-major acts
    __shared__ __align__(16) bf sRM2[64 * SR];   // 17,408 B
    __shared__ __align__(16) bf sT1 [128 * ST];  // 18,432 B transposed acts
    __shared__ __align__(16) bf sT2 [128 * ST];  // 18,432 B (also fp32 [128][34])
    __shared__ __align__(16) bf sAdj[64 * ST];   //  9,216 B adj, later vemb/gf/z
    __shared__ float sInv[64];
    __shared__ float sBatt[32];
    // total 81,280 B -> 2 blocks/CU

    bf* sVemb = sAdj;                 // 32 x SR bf16 (4352 elems <= 4608)
    bf* sS    = sT1;                  // 32 x SR bf16 (S[v][feat])
    bf* sEwnT = sT1 + 4608;           // 32 x ST bf16 (ewn^T[v][node])
    float* sT2f = (float*)sT2;        // 128 x 34 fp32 (vn2^T[feat][v])
    float* sGf  = (float*)sAdj;       // 128 fp32
    float* sZ   = ((float*)sAdj) + 128;

    const int tid  = threadIdx.x;
    const int g    = blockIdx.x;
    const int wave = tid >> 6;
    const int lane = tid & 63;
    const int l15  = lane & 15;
    const int q    = lane >> 4;
    const int kofs = q * 8;

    const bf* gWemb  = gWb;
    const bf* gWgcn  = gWb + 16384;
    const bf* gWaff1 = gWb + 2 * 16384;
    const bf* gW2    = gWb + 3 * 16384;   // aff_W2, straight [j][o]
    const bf* gWvn1  = gWb + 4 * 16384;
    const bf* gWvn2  = gWb + 5 * 16384;

    // ---------------- P0: stage x (bf16 RM) + adjacency + inv ----------------
    {
        const float4* gx = (const float4*)(x + (size_t)g * 8192);
#pragma unroll
        for (int t = 0; t < 8; ++t) {
            int i = tid + t * 256;
            int row = i >> 5, c4 = i & 31;
            float4 w = gx[i];
            bf4 tt;
            tt.v[0] = __float2bfloat16(w.x); tt.v[1] = __float2bfloat16(w.y);
            tt.v[2] = __float2bfloat16(w.z); tt.v[3] = __float2bfloat16(w.w);
            *(bf4*)(sRM1 + row * SR + c4 * 4) = tt;
        }
    }
    {
        const uint4* gA = (const uint4*)(Awords + ((size_t)g << 11));
        int r = tid >> 2, q4 = tid & 3;
        uint4 w0 = gA[tid * 2], w1 = gA[tid * 2 + 1];
        unsigned wd[8] = {w0.x, w0.y, w0.z, w0.w, w1.x, w1.y, w1.z, w1.w};
        if (q4 == (r >> 4)) wd[(r >> 1) & 7] += 1u << ((r & 1) * 16);  // self-loop
        float rs = 0.f;
#pragma unroll
        for (int wi = 0; wi < 8; ++wi) {
            unsigned lo = wd[wi] & 0xffffu, hi = wd[wi] >> 16;
            rs += (float)(lo + hi);
            bf* p = sAdj + r * ST + q4 * 16 + wi * 2;
            p[0] = __float2bfloat16((float)lo);
            p[1] = __float2bfloat16((float)hi);
        }
        rs += __shfl_xor(rs, 1);
        rs += __shfl_xor(rs, 2);
        if (q4 == 0) sInv[r] = rsqrtf(rs);   // rs = indeg + selfloop >= 1
    }
    __syncthreads();

    // ---------------- P1: h = x @ W_emb + b_emb -> sRM2 ----------------
    {
        f32x4 acc[8] = {};
        mma_block<SR, 128, 4, 8>(sRM1, gWemb, 16 * wave + l15, l15, kofs, acc);
#pragma unroll
        for (int nt = 0; nt < 8; ++nt) {
            float be = b_emb[nt * 16 + l15];
#pragma unroll
            for (int r = 0; r < 4; ++r)
                sRM2[(16 * wave + q * 4 + r) * SR + nt * 16 + l15] =
                    __float2bfloat16(acc[nt][r] + be);
        }
    }
    __syncthreads();

    // ------------- P2: hws^T = (h @ W_gcn) * inv[row] -> sT1 -------------
    {
        f32x4 acc[8] = {};
        mma_block<SR, 128, 4, 8>(sRM2, gWgcn, 16 * wave + l15, l15, kofs, acc);
        float iv[4];
#pragma unroll
        for (int r = 0; r < 4; ++r) iv[r] = sInv[16 * wave + q * 4 + r];
#pragma unroll
        for (int nt = 0; nt < 8; ++nt) {
            bf4 t;
#pragma unroll
            for (int r = 0; r < 4; ++r) t.v[r] = __float2bfloat16(acc[nt][r] * iv[r]);
            *(bf4*)(sT1 + (nt * 16 + l15) * ST + 16 * wave + q * 4) = t;
        }
    }
    __syncthreads();

    // --- P3: h_gcn = relu(inv[d]*(A' @ hws) + b_gcn) -> sRM1 (RM) + sT2 (T) ---
    {
        f32x4 acc[8] = {};
        mma_block<ST, ST, 2, 8>(sAdj, sT1, 16 * wave + l15, l15, kofs, acc);
        float iv[4];
#pragma unroll
        for (int r = 0; r < 4; ++r) iv[r] = sInv[16 * wave + q * 4 + r];
#pragma unroll
        for (int nt = 0; nt < 8; ++nt) {
            float bg = b_gcn[nt * 16 + l15];
            bf4 t;
#pragma unroll
            for (int r = 0; r < 4; ++r) {
                float v = fmaxf(acc[nt][r] * iv[r] + bg, 0.f);
                sRM1[(16 * wave + q * 4 + r) * SR + nt * 16 + l15] = __float2bfloat16(v);
                t.v[r] = __float2bfloat16(v);
            }
            *(bf4*)(sT2 + (nt * 16 + l15) * ST + 16 * wave + q * 4) = t;
        }
    }
    __syncthreads();

    // ---- P4: affh = relu(h_gcn @ aff_W1 + aff_b1) -> sRM2 ; stage vemb ----
    {
        const float4* gv4 = (const float4*)(vemb + (size_t)g * 4096);
#pragma unroll
        for (int t = 0; t < 4; ++t) {
            int i = tid + t * 256;      // 1024 float4 = 32x128
            int v = i >> 5, o4 = i & 31;
            float4 w = gv4[i];
            bf4 tt;
            tt.v[0] = __float2bfloat16(w.x); tt.v[1] = __float2bfloat16(w.y);
            tt.v[2] = __float2bfloat16(w.z); tt.v[3] = __float2bfloat16(w.w);
            *(bf4*)(sVemb + v * SR + o4 * 4) = tt;
        }
        f32x4 acc[8] = {};
        mma_block<SR, 128, 4, 8>(sRM1, gWaff1, 16 * wave + l15, l15, kofs, acc);
#pragma unroll
        for (int nt = 0; nt < 8; ++nt) {
            float ba = aff_b1[nt * 16 + l15];
#pragma unroll
            for (int r = 0; r < 4; ++r)
                sRM2[(16 * wave + q * 4 + r) * SR + nt * 16 + l15] =
                    __float2bfloat16(fmaxf(acc[nt][r] + ba, 0.f));
        }
    }
    __syncthreads();

    // ------- P5: S[v][j] = sum_o vemb[v][o]*aff_W2[j][o] -> sS ; batt -------
    {
        int mt = wave & 1, ng = wave >> 1;
        f32x4 acc[4] = {};
        mma_block<SR, 128, 4, 4>(sVemb, gW2, mt * 16 + l15, ng * 64 + l15, kofs, acc);
#pragma unroll
        for (int nt = 0; nt < 4; ++nt)
#pragma unroll
            for (int r = 0; r < 4; ++r)
                sS[(mt * 16 + q * 4 + r) * SR + ng * 64 + nt * 16 + l15] =
                    __float2bfloat16(acc[nt][r]);
        // batt[v] = sum_o aff_b2[o] * vemb[v][o]  (fp32, 8 lanes per v)
        int v = tid >> 3, sg = tid & 7;
        const float* gvv = vemb + (size_t)g * 4096 + v * 128 + sg * 16;
        float s = 0.f;
#pragma unroll
        for (int o = 0; o < 16; ++o) s += aff_b2[sg * 16 + o] * gvv[o];
        s += __shfl_xor(s, 1); s += __shfl_xor(s, 2); s += __shfl_xor(s, 4);
        if (sg == 0) sBatt[v] = s;
    }
    __syncthreads();

    // -- P6: att = (affh@S^T + batt)/sqrt(H); ew-normalize -> sEwnT [v][node] --
    {
        int m0 = 16 * wave;
        float gw[2][4], bt[2];
#pragma unroll
        for (int nt = 0; nt < 2; ++nt) {
            bt[nt] = sBatt[nt * 16 + l15];
#pragma unroll
            for (int r = 0; r < 4; ++r)
                gw[nt][r] = edge_w[(size_t)g * 2048 + (m0 + q * 4 + r) * 32 + nt * 16 + l15];
        }
        f32x4 acc[2] = {};
        mma_block<SR, SR, 4, 2>(sRM2, sS, m0 + l15, l15, kofs, acc);
        const float sc = 0.08838834764831845f;   // 1/sqrt(128)
        float e[2][4];
#pragma unroll
        for (int r = 0; r < 4; ++r) {
#pragma unroll
            for (int nt = 0; nt < 2; ++nt) {
                float att = (acc[nt][r] + bt[nt]) * sc;
                e[nt][r] = gw[nt][r] * (1.f + 1.f / (1.f + __expf(-att)));
            }
            float rs = e[0][r] + e[1][r];
            rs += __shfl_xor(rs, 1); rs += __shfl_xor(rs, 2);
            rs += __shfl_xor(rs, 4); rs += __shfl_xor(rs, 8);
            float ri = (rs == 0.f) ? 1.f : 1.f / rs;
            e[0][r] *= ri; e[1][r] *= ri;
        }
#pragma unroll
        for (int nt = 0; nt < 2; ++nt) {
            bf4 t;
#pragma unroll
            for (int r = 0; r < 4; ++r) t.v[r] = __float2bfloat16(e[nt][r]);
            *(bf4*)(sEwnT + (nt * 16 + l15) * ST + m0 + q * 4) = t;
        }
    }
    __syncthreads();

    // ---------- P7: vn = ewn^T @ h_gcn -> sRM1 rows 0..31 (RM) ----------
    {
        int mt = wave & 1, ng = wave >> 1;
        f32x4 acc[4] = {};
        mma_block<ST, ST, 2, 4>(sEwnT, sT2, mt * 16 + l15, ng * 64 + l15, kofs, acc);
#pragma unroll
        for (int nt = 0; nt < 4; ++nt)
#pragma unroll
            for (int r = 0; r < 4; ++r)
                sRM1[(mt * 16 + q * 4 + r) * SR + ng * 64 + nt * 16 + l15] =
                    __float2bfloat16(acc[nt][r]);
    }
    __syncthreads();

    // ---------- P8: z1 = relu(vn @ vn_W1 + vn_b1) -> sRM1 rows 32..63 ----------
    {
        int mt = wave & 1, ng = wave >> 1;
        f32x4 acc[4] = {};
        mma_block<SR, 128, 4, 4>(sRM1, gWvn1, mt * 16 + l15, ng * 64 + l15, kofs, acc);
#pragma unroll
        for (int nt = 0; nt < 4; ++nt) {
            float b = vn_b1[ng * 64 + nt * 16 + l15];
#pragma unroll
            for (int r = 0; r < 4; ++r)
                sRM1[(32 + mt * 16 + q * 4 + r) * SR + ng * 64 + nt * 16 + l15] =
                    __float2bfloat16(fmaxf(acc[nt][r] + b, 0.f));
        }
    }
    __syncthreads();

    // ---------- P9: vn2 = z1 @ vn_W2 + vn_b2 -> sT2f[feat][v] (fp32) ----------
    {
        int mt = wave & 1, ng = wave >> 1;
        f32x4 acc[4] = {};
        mma_block<SR, 128, 4, 4>(sRM1 + 32 * SR, gWvn2, mt * 16 + l15,
                                 ng * 64 + l15, kofs, acc);
#pragma unroll
        for (int nt = 0; nt < 4; ++nt) {
            float b = vn_b2[ng * 64 + nt * 16 + l15];
#pragma unroll
            for (int r = 0; r < 4; ++r)
                sT2f[(ng * 64 + nt * 16 + l15) * 34 + mt * 16 + q * 4 + r] =
                    acc[nt][r] + b;
        }
    }
    __syncthreads();

    // ---------------- P10: gf = mean over V ----------------
    if (tid < 128) {
        float s = 0.f;
#pragma unroll
        for (int v = 0; v < 32; ++v) s += sT2f[tid * 34 + v];
        sGf[tid] = s * (1.f / 32.f);
    }
    __syncthreads();

    // ---------------- P11: z = relu(gf @ mlp_W1 + b1) ----------------
    if (tid < 128) {
        float a = mlp_b1[tid];
#pragma unroll 4
        for (int k = 0; k < 128; ++k) a = fmaf(sGf[k], mlp_W1[k * 128 + tid], a);
        sZ[tid] = fmaxf(a, 0.f);
    }
    __syncthreads();

    // ---------------- P12: out = z @ mlp_W2 + b2 ----------------
    if (tid < 160) {
        int o = tid >> 4, jg = tid & 15;
        float p = 0.f;
#pragma unroll
        for (int t = 0; t < 8; ++t) {
            int j = jg * 8 + t;
            p = fmaf(sZ[j], mlp_W2[j * 10 + o], p);
        }
        p += __shfl_xor(p, 1); p += __shfl_xor(p, 2);
        p += __shfl_xor(p, 4); p += __shfl_xor(p, 8);
        if (jg == 0) out[g * 10 + o] = p + mlp_b2[o];
    }
}

extern "C" void kernel_launch(void* const* d_in, const int* in_sizes, int n_in,
                              void* d_out, int out_size, void* d_ws, size_t ws_size,
                              hipStream_t stream)
{
    const float* x       = (const float*)d_in[0];
    const int*   ei      = (const int*)  d_in[1];
    // d_in[2] = batch (unused)
    const float* edge_w  = (const float*)d_in[3];
    const float* vemb    = (const float*)d_in[4];
    const float* W_emb   = (const float*)d_in[5];
    const float* b_emb   = (const float*)d_in[6];
    const float* W_gcn   = (const float*)d_in[7];
    const float* b_gcn   = (const float*)d_in[8];
    const float* aff_W1  = (const float*)d_in[9];
    const float* aff_b1  = (const float*)d_in[10];
    const float* aff_W2  = (const float*)d_in[11];
    const float* aff_b2  = (const float*)d_in[12];
    const float* vn_W1   = (const float*)d_in[13];
    const float* vn_b1   = (const float*)d_in[14];
    const float* vn_W2   = (const float*)d_in[15];
    const float* vn_b2   = (const float*)d_in[16];
    const float* mlp_W1  = (const float*)d_in[17];
    const float* mlp_b1  = (const float*)d_in[18];
    const float* mlp_W2  = (const float*)d_in[19];
    const float* mlp_b2  = (const float*)d_in[20];

    unsigned* Awords = (unsigned*)d_ws;                       // 8 MB
    bf* gWb = (bf*)((char*)d_ws + 8u * 1024u * 1024u);        // 192 KB bf16 weights

    hipMemsetAsync(Awords, 0, (size_t)1024 * 2048 * sizeof(unsigned), stream);
    build_adj<<<dim3(EDGES / 256), dim3(256), 0, stream>>>(ei, Awords);
    conv_weights<<<dim3(64, 6), dim3(256), 0, stream>>>(
        W_emb, W_gcn, aff_W1, aff_W2, vn_W1, vn_W2, gWb);
    fused_graph<<<dim3(1024), dim3(256), 0, stream>>>(
        x, edge_w, vemb, gWb,
        b_emb, b_gcn, aff_b1, aff_b2, vn_b1, vn_b2,
        mlp_W1, mlp_b1, mlp_W2, mlp_b2, Awords, (float*)d_out);
}

// Round 3
// 194.672 us; speedup vs baseline: 2.2046x; 1.3222x over previous
//
#include <hip/hip_runtime.h>
#include <hip/hip_bf16.h>
#include <cstddef>

// G=1024 x 64 nodes, V=32, H=128, DIN=128, DOUT=10, E=1048576.
// R3: (1) edge bucketing by counting sort (NO device-scope atomics; the R2
//     build_adj's cross-XCD atomic RMWs were the hidden ~100+ us),
//     (2) weights pre-swizzled into MFMA-fragment-linear order -> each wave's
//     B-frag load is a contiguous 1KB coalesced stream,
//     (3) disjoint N-slice per wave (4x less B traffic) + one-phase-ahead
//     register prefetch of B (global->VGPR loads survive barriers),
//     (4) tail MLP moved to its own kernel (better parallelism).

#define EDGES 1048576
#define SR 136   // row stride (bf16) of row-major [node][feat] LDS tiles
#define ST 72    // row stride (bf16) of transposed [feat][node] LDS tiles

typedef __attribute__((ext_vector_type(8))) short short8;
typedef __attribute__((ext_vector_type(4))) float f32x4;
typedef __hip_bfloat16 bf;
struct __align__(8) bf4 { bf v[4]; };

// ---------------- counting sort: s1 histogram ----------------
__global__ __launch_bounds__(256) void edge_hist(const int* __restrict__ ei,
                                                 unsigned* __restrict__ H)
{
    __shared__ unsigned lh[1024];
    int tid = threadIdx.x, b = blockIdx.x;
    for (int t = tid; t < 1024; t += 256) lh[t] = 0;
    __syncthreads();
    int base = b * 4096;
#pragma unroll 4
    for (int t = 0; t < 16; ++t) {
        int s = ei[base + t * 256 + tid];
        atomicAdd(&lh[s >> 6], 1u);      // LDS atomic
    }
    __syncthreads();
    for (int t = tid; t < 1024; t += 256) H[b * 1024 + t] = lh[t];
}

// ---------------- s2a: per-bin running offsets across blocks ----------------
__global__ __launch_bounds__(256) void scan_blocks(unsigned* __restrict__ H,
                                                   unsigned* __restrict__ Tot)
{
    int g = blockIdx.x * 256 + threadIdx.x;
    unsigned run = 0;
    for (int b = 0; b < 256; ++b) {
        unsigned t = H[b * 1024 + g];
        H[b * 1024 + g] = run;
        run += t;
    }
    Tot[g] = run;
}

// ---------------- s2b: exclusive scan of bin totals ----------------
__global__ __launch_bounds__(1024) void scan_bins(const unsigned* __restrict__ Tot,
                                                  unsigned* __restrict__ Base)
{
    __shared__ unsigned a[1024];
    int t = threadIdx.x;
    a[t] = Tot[t];
    __syncthreads();
    for (int off = 1; off < 1024; off <<= 1) {
        unsigned v = (t >= off) ? a[t - off] : 0u;
        __syncthreads();
        a[t] += v;
        __syncthreads();
    }
    Base[t] = a[t] - Tot[t];
}

// ---------------- s3: scatter edges into per-graph segments ----------------
__global__ __launch_bounds__(256) void edge_scatter(const int* __restrict__ ei,
                                                    const unsigned* __restrict__ H,
                                                    const unsigned* __restrict__ Base,
                                                    unsigned short* __restrict__ sorted)
{
    __shared__ unsigned lh[1024];
    int tid = threadIdx.x, b = blockIdx.x;
    for (int t = tid; t < 1024; t += 256) lh[t] = 0;
    __syncthreads();
    int base = b * 4096;
    for (int t = 0; t < 16; ++t) {
        int e = base + t * 256 + tid;
        int s = ei[e], d = ei[EDGES + e];
        int g = s >> 6;
        unsigned r = atomicAdd(&lh[g], 1u);          // LDS atomic rank
        unsigned pos = Base[g] + H[b * 1024 + g] + r;
        sorted[pos] = (unsigned short)(((d & 63) << 6) | (s & 63));
    }
}

// ---------------- weight conversion to fragment-linear bf16 ----------------
// Store B[n][k] (n=output col, k=contraction) as:
//   off = ((n>>4)*4 + (k>>5))*512 + (n&15)*32 + (k&31)
// so a wave's (nblk,ks) fragment load = 1KB contiguous.
// m in {0,1,2,4,5}: B = W^T (B[n][k]=W[k][n]); m==3 (aff_W2): B[n][k]=W[n][k].
__global__ __launch_bounds__(256) void conv_weights(
    const float* __restrict__ w0, const float* __restrict__ w1,
    const float* __restrict__ w2, const float* __restrict__ w3,
    const float* __restrict__ w4, const float* __restrict__ w5,
    bf* __restrict__ outw)
{
    int m = blockIdx.y;
    const float* src = m==0?w0: m==1?w1: m==2?w2: m==3?w3: m==4?w4: w5;
    int idx = blockIdx.x * 256 + threadIdx.x;  // n*128+k
    int n = idx >> 7, k = idx & 127;
    float v = (m == 3) ? src[n * 128 + k] : src[k * 128 + n];
    int off = (((n >> 4) * 4 + (k >> 5)) * 512) + (n & 15) * 32 + (k & 31);
    outw[m * 16384 + off] = __float2bfloat16(v);
}

// B-prefetch: 8 frags (nt=2 x ks=4) for this wave's N-slice, 1KB contiguous per frag
__device__ __forceinline__ void loadB(const bf* __restrict__ gW, int wv, int l15,
                                      int kofs, short8* B)
{
#pragma unroll
    for (int nt = 0; nt < 2; ++nt)
#pragma unroll
        for (int ks = 0; ks < 4; ++ks)
            B[nt * 4 + ks] = *(const short8*)(gW + (((wv * 2 + nt) * 4 + ks) * 512)
                                              + l15 * 32 + kofs);
}

template<int MT, int KS, int SA>
__device__ __forceinline__ void mmaAB(const bf* sA, int rowA, int l15, int kofs,
                                      const short8* B, f32x4 (*acc)[2])
{
#pragma unroll
    for (int ks = 0; ks < KS; ++ks) {
        short8 a[MT];
#pragma unroll
        for (int m = 0; m < MT; ++m)
            a[m] = *(const short8*)(sA + (rowA + m * 16 + l15) * SA + ks * 32 + kofs);
#pragma unroll
        for (int m = 0; m < MT; ++m)
#pragma unroll
            for (int nt = 0; nt < 2; ++nt)
                acc[m][nt] = __builtin_amdgcn_mfma_f32_16x16x32_bf16(
                    a[m], B[nt * 4 + ks], acc[m][nt], 0, 0, 0);
    }
}

template<int MT, int KS, int SA, int SB>
__device__ __forceinline__ void mmaABlds(const bf* sA, int rowA, const bf* sB, int rowB,
                                         int l15, int kofs, f32x4 (*acc)[2])
{
#pragma unroll
    for (int ks = 0; ks < KS; ++ks) {
        short8 bb[2];
#pragma unroll
        for (int nt = 0; nt < 2; ++nt)
            bb[nt] = *(const short8*)(sB + (rowB + nt * 16 + l15) * SB + ks * 32 + kofs);
        short8 a[MT];
#pragma unroll
        for (int m = 0; m < MT; ++m)
            a[m] = *(const short8*)(sA + (rowA + m * 16 + l15) * SA + ks * 32 + kofs);
#pragma unroll
        for (int m = 0; m < MT; ++m)
#pragma unroll
            for (int nt = 0; nt < 2; ++nt)
                acc[m][nt] = __builtin_amdgcn_mfma_f32_16x16x32_bf16(
                    a[m], bb[nt], acc[m][nt], 0, 0, 0);
    }
}

__global__ __launch_bounds__(256, 2) void fused_graph(
    const float* __restrict__ x, const float* __restrict__ edge_w,
    const float* __restrict__ vemb, const bf* __restrict__ gWb,
    const float* __restrict__ b_emb,  const float* __restrict__ b_gcn,
    const float* __restrict__ aff_b1, const float* __restrict__ aff_b2,
    const float* __restrict__ vn_b1,  const float* __restrict__ vn_b2,
    const unsigned short* __restrict__ sorted,
    const unsigned* __restrict__ Tot, const unsigned* __restrict__ Base,
    float* __restrict__ gfout)
{
    __shared__ __align__(16) bf sRM1[64 * SR];   // 17,408 B
    __shared__ __align__(16) bf sRM2[64 * SR];   // 17,408 B
    __shared__ __align__(16) bf sT1 [128 * ST];  // 18,432 B (cnt / hws^T / S+ewnT)
    __shared__ __align__(16) bf sT2 [128 * ST];  // 18,432 B (hgcn^T / vn2^T fp32)
    __shared__ __align__(16) bf sAdj[64 * ST];   //  9,216 B (adj / vemb)
    __shared__ float sInv[64];
    __shared__ float sBatt[32];
    // total 81,280 B -> 2 blocks/CU

    unsigned* cnt = (unsigned*)sT1;        // 1024 u32 words (u8-packed counts)
    bf* sVemb = sAdj;                      // 32 x SR after P3
    bf* sS    = sT1;                       // 32 x SR (S[v][feat])
    bf* sEwnT = sT1 + 4608;                // 32 x ST (ewn^T[v][node])
    float* sT2f = (float*)sT2;             // 128 x 34 fp32

    const int tid = threadIdx.x;
    const int g = blockIdx.x;
    const int wv = tid >> 6;
    const int lane = tid & 63;
    const int l15 = lane & 15;
    const int q = lane >> 4;
    const int kofs = q * 8;

    // ---- entry prefetches (global->VGPR; independent of all barriers) ----
    short8 Bp[8], Bn[8];
    loadB(gWb, wv, l15, kofs, Bp);                 // W_emb   (P1)
    loadB(gWb + 16384, wv, l15, kofs, Bn);         // W_gcn   (P2)
    float4 xreg[8];
    const float4* gx = (const float4*)(x + (size_t)g * 8192);
#pragma unroll
    for (int t = 0; t < 8; ++t) xreg[t] = gx[tid + t * 256];
    float4 vreg[4];
    const float4* gv = (const float4*)(vemb + (size_t)g * 4096);
#pragma unroll
    for (int t = 0; t < 4; ++t) vreg[t] = gv[tid + t * 256];
    float ewreg[2][4];
#pragma unroll
    for (int nt = 0; nt < 2; ++nt)
#pragma unroll
        for (int r = 0; r < 4; ++r)
            ewreg[nt][r] = edge_w[(size_t)g * 2048 + (wv * 16 + q * 4 + r) * 32
                                  + nt * 16 + l15];
    float bias_e[2], bias_g[2], bias_a1[2], bias_v1[2], bias_v2[2];
#pragma unroll
    for (int nt = 0; nt < 2; ++nt) {
        int n = wv * 32 + nt * 16 + l15;
        bias_e[nt] = b_emb[n];  bias_g[nt] = b_gcn[n]; bias_a1[nt] = aff_b1[n];
        bias_v1[nt] = vn_b1[n]; bias_v2[nt] = vn_b2[n];
    }
    unsigned ecnt = Tot[g], ebase = Base[g];

    // ---- P0a: zero counts ----
#pragma unroll
    for (int t = 0; t < 4; ++t) cnt[tid * 4 + t] = 0u;
    __syncthreads();
    // ---- P0b: build counts (LDS atomics) + stage x ----
    for (unsigned i = tid; i < ecnt; i += 256) {
        unsigned w = sorted[ebase + i];
        unsigned d = w >> 6, s = w & 63u;
        atomicAdd(&cnt[d * 16 + (s >> 2)], 1u << ((s & 3u) * 8));
    }
#pragma unroll
    for (int t = 0; t < 8; ++t) {
        int i = tid + t * 256;
        int row = i >> 5, c4 = i & 31;
        float4 w = xreg[t];
        bf4 tt;
        tt.v[0] = __float2bfloat16(w.x); tt.v[1] = __float2bfloat16(w.y);
        tt.v[2] = __float2bfloat16(w.z); tt.v[3] = __float2bfloat16(w.w);
        *(bf4*)(sRM1 + row * SR + c4 * 4) = tt;
    }
    __syncthreads();
    // ---- P0c: counts -> bf16 adjacency (+self-loop) + inv=rsqrt(deg) ----
    {
        int r = tid >> 2, q4 = tid & 3;
        float rs = 0.f;
#pragma unroll
        for (int t = 0; t < 4; ++t) {
            unsigned wd = cnt[r * 16 + q4 * 4 + t];
#pragma unroll
            for (int j = 0; j < 4; ++j) {
                int s = (q4 * 4 + t) * 4 + j;
                float v = (float)((wd >> (j * 8)) & 255u) + (s == r ? 1.f : 0.f);
                rs += v;
                sAdj[r * ST + s] = __float2bfloat16(v);
            }
        }
        rs += __shfl_xor(rs, 1);
        rs += __shfl_xor(rs, 2);
        if (q4 == 0) sInv[r] = rsqrtf(rs);
    }
    __syncthreads();

    // ---- P1: h = x @ W_emb^T-frag + b_emb -> sRM2 ----
    {
        f32x4 acc[4][2] = {};
        mmaAB<4, 4, SR>(sRM1, 0, l15, kofs, Bp, acc);
        loadB(gWb + 2 * 16384, wv, l15, kofs, Bp);   // aff_W1 (P4)
#pragma unroll
        for (int m = 0; m < 4; ++m)
#pragma unroll
            for (int nt = 0; nt < 2; ++nt)
#pragma unroll
                for (int r = 0; r < 4; ++r)
                    sRM2[(m * 16 + q * 4 + r) * SR + wv * 32 + nt * 16 + l15] =
                        __float2bfloat16(acc[m][nt][r] + bias_e[nt]);
    }
    __syncthreads();

    // ---- P2: hws^T = (h @ W_gcn) * inv[row] -> sT1 ----
    {
        f32x4 acc[4][2] = {};
        mmaAB<4, 4, SR>(sRM2, 0, l15, kofs, Bn, acc);
        loadB(gWb + 3 * 16384, wv, l15, kofs, Bn);   // aff_W2 (P5)
#pragma unroll
        for (int m = 0; m < 4; ++m)
#pragma unroll
            for (int nt = 0; nt < 2; ++nt) {
                bf4 tv;
#pragma unroll
                for (int r = 0; r < 4; ++r)
                    tv.v[r] = __float2bfloat16(acc[m][nt][r] * sInv[m * 16 + q * 4 + r]);
                *(bf4*)(sT1 + (wv * 32 + nt * 16 + l15) * ST + m * 16 + q * 4) = tv;
            }
    }
    __syncthreads();

    // ---- P3: h_gcn = relu(inv[d]*(A' @ hws) + b_gcn) -> sRM1 + sT2 ----
    {
        f32x4 acc[4][2] = {};
        mmaABlds<4, 2, ST, ST>(sAdj, 0, sT1, wv * 32, l15, kofs, acc);
#pragma unroll
        for (int m = 0; m < 4; ++m)
#pragma unroll
            for (int nt = 0; nt < 2; ++nt) {
                bf4 tv;
#pragma unroll
                for (int r = 0; r < 4; ++r) {
                    float v = fmaxf(acc[m][nt][r] * sInv[m * 16 + q * 4 + r] + bias_g[nt], 0.f);
                    sRM1[(m * 16 + q * 4 + r) * SR + wv * 32 + nt * 16 + l15] = __float2bfloat16(v);
                    tv.v[r] = __float2bfloat16(v);
                }
                *(bf4*)(sT2 + (wv * 32 + nt * 16 + l15) * ST + m * 16 + q * 4) = tv;
            }
    }
    __syncthreads();

    // ---- P4: affh = relu(h_gcn @ aff_W1 + aff_b1) -> sRM2 ; vemb regs -> LDS ----
    {
#pragma unroll
        for (int t = 0; t < 4; ++t) {
            int i = tid + t * 256;
            int v = i >> 5, o4 = i & 31;
            float4 w = vreg[t];
            bf4 tt;
            tt.v[0] = __float2bfloat16(w.x); tt.v[1] = __float2bfloat16(w.y);
            tt.v[2] = __float2bfloat16(w.z); tt.v[3] = __float2bfloat16(w.w);
            *(bf4*)(sVemb + v * SR + o4 * 4) = tt;
        }
        f32x4 acc[4][2] = {};
        mmaAB<4, 4, SR>(sRM1, 0, l15, kofs, Bp, acc);
        loadB(gWb + 4 * 16384, wv, l15, kofs, Bp);   // vn_W1 (P8)
#pragma unroll
        for (int m = 0; m < 4; ++m)
#pragma unroll
            for (int nt = 0; nt < 2; ++nt)
#pragma unroll
                for (int r = 0; r < 4; ++r)
                    sRM2[(m * 16 + q * 4 + r) * SR + wv * 32 + nt * 16 + l15] =
                        __float2bfloat16(fmaxf(acc[m][nt][r] + bias_a1[nt], 0.f));
    }
    __syncthreads();

    // ---- P5: S[v][j] = sum_o vemb[v][o]*aff_W2[j][o] -> sS ; batt ----
    {
        f32x4 acc[2][2] = {};
        mmaAB<2, 4, SR>(sVemb, 0, l15, kofs, Bn, acc);
        loadB(gWb + 5 * 16384, wv, l15, kofs, Bn);   // vn_W2 (P9)
#pragma unroll
        for (int m = 0; m < 2; ++m)
#pragma unroll
            for (int nt = 0; nt < 2; ++nt)
#pragma unroll
                for (int r = 0; r < 4; ++r)
                    sS[(m * 16 + q * 4 + r) * SR + wv * 32 + nt * 16 + l15] =
                        __float2bfloat16(acc[m][nt][r]);
        int v = tid >> 3, sg = tid & 7;
        float s = 0.f;
        const bf* pv = sVemb + v * SR + sg * 16;
        const float* pb = aff_b2 + sg * 16;
#pragma unroll
        for (int o = 0; o < 16; ++o) s += pb[o] * __bfloat162float(pv[o]);
        s += __shfl_xor(s, 1); s += __shfl_xor(s, 2); s += __shfl_xor(s, 4);
        if (sg == 0) sBatt[v] = s;
    }
    __syncthreads();

    // ---- P6: att -> sigmoid gate -> row-normalize -> sEwnT[v][node] ----
    {
        f32x4 acc[1][2] = {};
        mmaABlds<1, 4, SR, SR>(sRM2, wv * 16, sS, 0, l15, kofs, acc);
        const float sc = 0.08838834764831845f;   // 1/sqrt(128)
        float bt[2] = { sBatt[l15], sBatt[16 + l15] };
        float e[2][4];
#pragma unroll
        for (int r = 0; r < 4; ++r) {
#pragma unroll
            for (int nt = 0; nt < 2; ++nt) {
                float att = (acc[0][nt][r] + bt[nt]) * sc;
                e[nt][r] = ewreg[nt][r] * (1.f + 1.f / (1.f + __expf(-att)));
            }
            float rs = e[0][r] + e[1][r];
            rs += __shfl_xor(rs, 1); rs += __shfl_xor(rs, 2);
            rs += __shfl_xor(rs, 4); rs += __shfl_xor(rs, 8);
            float ri = 1.f / rs;
            e[0][r] *= ri; e[1][r] *= ri;
        }
#pragma unroll
        for (int nt = 0; nt < 2; ++nt) {
            bf4 tv;
#pragma unroll
            for (int r = 0; r < 4; ++r) tv.v[r] = __float2bfloat16(e[nt][r]);
            *(bf4*)(sEwnT + (nt * 16 + l15) * ST + wv * 16 + q * 4) = tv;
        }
    }
    __syncthreads();

    // ---- P7: vn = ewn^T @ h_gcn -> sRM1 rows 0..31 (RM) ----
    {
        f32x4 acc[2][2] = {};
        mmaABlds<2, 2, ST, ST>(sEwnT, 0, sT2, wv * 32, l15, kofs, acc);
#pragma unroll
        for (int m = 0; m < 2; ++m)
#pragma unroll
            for (int nt = 0; nt < 2; ++nt)
#pragma unroll
                for (int r = 0; r < 4; ++r)
                    sRM1[(m * 16 + q * 4 + r) * SR + wv * 32 + nt * 16 + l15] =
                        __float2bfloat16(acc[m][nt][r]);
    }
    __syncthreads();

    // ---- P8: z1 = relu(vn @ vn_W1 + vn_b1) -> sRM1 rows 32..63 ----
    {
        f32x4 acc[2][2] = {};
        mmaAB<2, 4, SR>(sRM1, 0, l15, kofs, Bp, acc);
#pragma unroll
        for (int m = 0; m < 2; ++m)
#pragma unroll
            for (int nt = 0; nt < 2; ++nt)
#pragma unroll
                for (int r = 0; r < 4; ++r)
                    sRM1[(32 + m * 16 + q * 4 + r) * SR + wv * 32 + nt * 16 + l15] =
                        __float2bfloat16(fmaxf(acc[m][nt][r] + bias_v1[nt], 0.f));
    }
    __syncthreads();

    // ---- P9: vn2 = z1 @ vn_W2 + vn_b2 -> sT2f[feat][v] fp32 ----
    {
        f32x4 acc[2][2] = {};
        mmaAB<2, 4, SR>(sRM1 + 32 * SR, 0, l15, kofs, Bn, acc);
#pragma unroll
        for (int m = 0; m < 2; ++m)
#pragma unroll
            for (int nt = 0; nt < 2; ++nt)
#pragma unroll
                for (int r = 0; r < 4; ++r)
                    sT2f[(wv * 32 + nt * 16 + l15) * 34 + m * 16 + q * 4 + r] =
                        acc[m][nt][r] + bias_v2[nt];
    }
    __syncthreads();

    // ---- P10: gf = mean over V -> global ----
    if (tid < 128) {
        float s = 0.f;
#pragma unroll
        for (int v = 0; v < 32; ++v) s += sT2f[tid * 34 + v];
        gfout[g * 128 + tid] = s * 0.03125f;
    }
}

// ---------------- tail: out = relu(gf@W1+b1)@W2+b2 ----------------
__global__ __launch_bounds__(256) void tail_mlp(const float* __restrict__ gf,
                                                const float* __restrict__ W1,
                                                const float* __restrict__ b1,
                                                const float* __restrict__ W2,
                                                const float* __restrict__ b2,
                                                float* __restrict__ out)
{
    __shared__ float z[2][128];
    int tid = threadIdx.x;
    int half = tid >> 7, o = tid & 127;
    const float* gr = gf + (blockIdx.x * 2 + half) * 128;
    float a = b1[o];
#pragma unroll 4
    for (int k = 0; k < 128; ++k) a = fmaf(gr[k], W1[k * 128 + o], a);
    z[half][o] = fmaxf(a, 0.f);
    __syncthreads();
    if (tid < 160) {
        int grp = tid >> 3, jg = tid & 7;
        int r2 = grp / 10, oo = grp % 10;
        float p = 0.f;
#pragma unroll
        for (int t = 0; t < 16; ++t) {
            int j = jg * 16 + t;
            p = fmaf(z[r2][j], W2[j * 10 + oo], p);
        }
        p += __shfl_xor(p, 1); p += __shfl_xor(p, 2); p += __shfl_xor(p, 4);
        if (jg == 0) out[(blockIdx.x * 2 + r2) * 10 + oo] = p + b2[oo];
    }
}

extern "C" void kernel_launch(void* const* d_in, const int* in_sizes, int n_in,
                              void* d_out, int out_size, void* d_ws, size_t ws_size,
                              hipStream_t stream)
{
    const float* x       = (const float*)d_in[0];
    const int*   ei      = (const int*)  d_in[1];
    // d_in[2] = batch (unused)
    const float* edge_w  = (const float*)d_in[3];
    const float* vemb    = (const float*)d_in[4];
    const float* W_emb   = (const float*)d_in[5];
    const float* b_emb   = (const float*)d_in[6];
    const float* W_gcn   = (const float*)d_in[7];
    const float* b_gcn   = (const float*)d_in[8];
    const float* aff_W1  = (const float*)d_in[9];
    const float* aff_b1  = (const float*)d_in[10];
    const float* aff_W2  = (const float*)d_in[11];
    const float* aff_b2  = (const float*)d_in[12];
    const float* vn_W1   = (const float*)d_in[13];
    const float* vn_b1   = (const float*)d_in[14];
    const float* vn_W2   = (const float*)d_in[15];
    const float* vn_b2   = (const float*)d_in[16];
    const float* mlp_W1  = (const float*)d_in[17];
    const float* mlp_b1  = (const float*)d_in[18];
    const float* mlp_W2  = (const float*)d_in[19];
    const float* mlp_b2  = (const float*)d_in[20];

    char* ws = (char*)d_ws;
    unsigned short* sorted = (unsigned short*)ws;               // 2 MB
    unsigned* H    = (unsigned*)(ws + (2u << 20));              // 1 MB
    unsigned* Tot  = (unsigned*)(ws + (3u << 20));              // 4 KB
    unsigned* Base = (unsigned*)(ws + (3u << 20) + 4096);       // 4 KB
    bf*       gWb  = (bf*)      (ws + (4u << 20));              // 192 KB
    float*   gfbuf = (float*)   (ws + (5u << 20));              // 512 KB

    edge_hist  <<<dim3(256), dim3(256), 0, stream>>>(ei, H);
    scan_blocks<<<dim3(4),   dim3(256), 0, stream>>>(H, Tot);
    scan_bins  <<<dim3(1),   dim3(1024),0, stream>>>(Tot, Base);
    edge_scatter<<<dim3(256),dim3(256), 0, stream>>>(ei, H, Base, sorted);
    conv_weights<<<dim3(64, 6), dim3(256), 0, stream>>>(
        W_emb, W_gcn, aff_W1, aff_W2, vn_W1, vn_W2, gWb);
    fused_graph<<<dim3(1024), dim3(256), 0, stream>>>(
        x, edge_w, vemb, gWb, b_emb, b_gcn, aff_b1, aff_b2,
        vn_b1, vn_b2, sorted, Tot, Base, gfbuf);
    tail_mlp<<<dim3(512), dim3(256), 0, stream>>>(
        gfbuf, mlp_W1, mlp_b1, mlp_W2, mlp_b2, (float*)d_out);
}